// Round 1
// baseline (471.624 us; speedup 1.0000x reference)
//
#include <hip/hip_runtime.h>
#include <hip/hip_bf16.h>

// Cross-attention: B=8, S_ENC=2048, S_DEC=1024, D_IN=512, UNITS=512.
// Strategy: split-bf16 (hi+lo) 3-MFMA fp32 emulation for projections + QK^T
// (softmax amplifies logit error exponentially; logits ~N(0,22.6) unscaled),
// plain bf16 MFMA for PV. All MFMA: v_mfma_f32_16x16x32_bf16.
//
// ws layout (128 MB):
//   qh  [8][1024][512] bf16 @ 0      (8 MB)
//   ql                      @ 8 MB
//   kh  [8][2048][512] bf16 @ 16 MB  (16 MB)
//   kl                      @ 32 MB
//   vt  [8][512][2048] bf16 @ 48 MB  (16 MB, transposed for PV B-frags)
//   S   [8][1024][2048] f32 @ 64 MB  (64 MB)
//   P   [8][1024][2048] bf16 @ 16 MB (aliases kh/kl — dead after score GEMM)

typedef __attribute__((ext_vector_type(8))) __bf16 bf16x8;
typedef __attribute__((ext_vector_type(4))) float f32x4;

#define MFMA16(a, b, c) __builtin_amdgcn_mfma_f32_16x16x32_bf16(a, b, c, 0, 0, 0)

__device__ __forceinline__ void split_store(__bf16* hp, __bf16* lp, float x) {
    __bf16 h = (__bf16)x;
    *hp = h;
    *lp = (__bf16)(x - (float)h);
}

// C[M,64-col-slab] = A[M,512] * W[512,512], output split bf16 (MODE 0) or
// transposed single bf16 (MODE 1, v: vt[b][n][s], 2048 rows/batch).
template <int MODE>
__launch_bounds__(256)
__global__ void proj_kernel(const float* __restrict__ A, const float* __restrict__ W,
                            __bf16* __restrict__ o1, __bf16* __restrict__ o2) {
    __shared__ __bf16 Ah[64][40], Al[64][40], Wh[64][40], Wl[64][40];
    const int tid = threadIdx.x;
    const int wave = tid >> 6, lane = tid & 63;
    const int quad = lane >> 4, m16 = lane & 15;
    const int row0 = blockIdx.y * 64, col0 = blockIdx.x * 64;

    f32x4 acc[4];
#pragma unroll
    for (int nt = 0; nt < 4; ++nt) acc[nt] = (f32x4){0.f, 0.f, 0.f, 0.f};

    const int ar = tid >> 2, au = (tid & 3) * 8;   // A stage: 64 rows x 32 u
    const int wu = tid >> 3, wn = (tid & 7) * 8;   // W stage: 32 u x 64 n (transposed into LDS)

    for (int ks = 0; ks < 16; ++ks) {
        const int u0 = ks * 32;
        __syncthreads();
        {
            const float* Ap = A + (size_t)(row0 + ar) * 512 + u0 + au;
            float4 a0 = *(const float4*)Ap;
            float4 a1 = *(const float4*)(Ap + 4);
            float av[8] = {a0.x, a0.y, a0.z, a0.w, a1.x, a1.y, a1.z, a1.w};
#pragma unroll
            for (int i = 0; i < 8; ++i) split_store(&Ah[ar][au + i], &Al[ar][au + i], av[i]);

            const float* Wp = W + (size_t)(u0 + wu) * 512 + col0 + wn;
            float4 w0 = *(const float4*)Wp;
            float4 w1 = *(const float4*)(Wp + 4);
            float wv[8] = {w0.x, w0.y, w0.z, w0.w, w1.x, w1.y, w1.z, w1.w};
#pragma unroll
            for (int i = 0; i < 8; ++i) split_store(&Wh[wn + i][wu], &Wl[wn + i][wu], wv[i]);
        }
        __syncthreads();
        bf16x8 ah = *(const bf16x8*)&Ah[wave * 16 + m16][quad * 8];
        bf16x8 al = *(const bf16x8*)&Al[wave * 16 + m16][quad * 8];
#pragma unroll
        for (int nt = 0; nt < 4; ++nt) {
            bf16x8 bh = *(const bf16x8*)&Wh[nt * 16 + m16][quad * 8];
            bf16x8 bl = *(const bf16x8*)&Wl[nt * 16 + m16][quad * 8];
            acc[nt] = MFMA16(ah, bh, acc[nt]);
            acc[nt] = MFMA16(ah, bl, acc[nt]);
            acc[nt] = MFMA16(al, bh, acc[nt]);
        }
    }

#pragma unroll
    for (int nt = 0; nt < 4; ++nt) {
#pragma unroll
        for (int r = 0; r < 4; ++r) {
            int row = row0 + wave * 16 + quad * 4 + r;
            int col = col0 + nt * 16 + m16;
            float x = acc[nt][r];
            if (MODE == 0) {
                __bf16 h = (__bf16)x;
                o1[(size_t)row * 512 + col] = h;
                o2[(size_t)row * 512 + col] = (__bf16)(x - (float)h);
            } else {
                int b = row >> 11, s = row & 2047;
                o1[((size_t)b * 512 + col) * 2048 + s] = (__bf16)x;
            }
        }
    }
}

// S[b, q0:q0+64, s0:s0+64] = q . k^T, split 3-MFMA.
__launch_bounds__(256)
__global__ void score_kernel(const __bf16* __restrict__ qh, const __bf16* __restrict__ ql,
                             const __bf16* __restrict__ kh, const __bf16* __restrict__ kl,
                             float* __restrict__ S) {
    __shared__ __bf16 Qh[64][40], Ql[64][40], Kh[64][40], Kl[64][40];
    const int tid = threadIdx.x;
    const int wave = tid >> 6, lane = tid & 63;
    const int quad = lane >> 4, m16 = lane & 15;
    const int s0 = blockIdx.x * 64, q0 = blockIdx.y * 64, b = blockIdx.z;

    f32x4 acc[4];
#pragma unroll
    for (int st = 0; st < 4; ++st) acc[st] = (f32x4){0.f, 0.f, 0.f, 0.f};

    const int r = tid >> 2, u = (tid & 3) * 8;
    const __bf16* qhp = qh + ((size_t)b * 1024 + q0 + r) * 512 + u;
    const __bf16* qlp = ql + ((size_t)b * 1024 + q0 + r) * 512 + u;
    const __bf16* khp = kh + ((size_t)b * 2048 + s0 + r) * 512 + u;
    const __bf16* klp = kl + ((size_t)b * 2048 + s0 + r) * 512 + u;

    for (int ks = 0; ks < 16; ++ks) {
        __syncthreads();
        *(bf16x8*)&Qh[r][u] = *(const bf16x8*)(qhp + ks * 32);
        *(bf16x8*)&Ql[r][u] = *(const bf16x8*)(qlp + ks * 32);
        *(bf16x8*)&Kh[r][u] = *(const bf16x8*)(khp + ks * 32);
        *(bf16x8*)&Kl[r][u] = *(const bf16x8*)(klp + ks * 32);
        __syncthreads();
        bf16x8 ah = *(const bf16x8*)&Qh[wave * 16 + m16][quad * 8];
        bf16x8 al = *(const bf16x8*)&Ql[wave * 16 + m16][quad * 8];
#pragma unroll
        for (int st = 0; st < 4; ++st) {
            bf16x8 bh = *(const bf16x8*)&Kh[st * 16 + m16][quad * 8];
            bf16x8 bl = *(const bf16x8*)&Kl[st * 16 + m16][quad * 8];
            acc[st] = MFMA16(ah, bh, acc[st]);
            acc[st] = MFMA16(ah, bl, acc[st]);
            acc[st] = MFMA16(al, bh, acc[st]);
        }
    }

#pragma unroll
    for (int st = 0; st < 4; ++st) {
#pragma unroll
        for (int rr = 0; rr < 4; ++rr) {
            S[((size_t)b * 1024 + q0 + wave * 16 + quad * 4 + rr) * 2048 + s0 + st * 16 + m16] =
                acc[st][rr];
        }
    }
}

// Row softmax over 2048 cols, fp32 in -> bf16 out. One block per row.
__launch_bounds__(256)
__global__ void softmax_kernel(const float* __restrict__ S, __bf16* __restrict__ P) {
    const int row = blockIdx.x;
    const int tid = threadIdx.x;
    const int wave = tid >> 6, lane = tid & 63;
    __shared__ float red[8];

    const float* sp = S + (size_t)row * 2048 + tid * 8;
    float4 x0 = *(const float4*)sp;
    float4 x1 = *(const float4*)(sp + 4);
    float v[8] = {x0.x, x0.y, x0.z, x0.w, x1.x, x1.y, x1.z, x1.w};

    float mx = v[0];
#pragma unroll
    for (int i = 1; i < 8; ++i) mx = fmaxf(mx, v[i]);
#pragma unroll
    for (int off = 32; off > 0; off >>= 1) mx = fmaxf(mx, __shfl_down(mx, off));
    if (lane == 0) red[wave] = mx;
    __syncthreads();
    if (tid == 0) red[4] = fmaxf(fmaxf(red[0], red[1]), fmaxf(red[2], red[3]));
    __syncthreads();
    mx = red[4];

    float e[8];
    float sum = 0.f;
#pragma unroll
    for (int i = 0; i < 8; ++i) {
        e[i] = exp2f((v[i] - mx) * 1.44269504088896f);
        sum += e[i];
    }
#pragma unroll
    for (int off = 32; off > 0; off >>= 1) sum += __shfl_down(sum, off);
    if (lane == 0) red[wave] = sum;
    __syncthreads();
    if (tid == 0) red[5] = red[0] + red[1] + red[2] + red[3];
    __syncthreads();
    float inv = 1.0f / red[5];

    bf16x8 ov;
#pragma unroll
    for (int i = 0; i < 8; ++i) ov[i] = (__bf16)(e[i] * inv);
    *(bf16x8*)(P + (size_t)row * 2048 + tid * 8) = ov;
}

// out[b, q0:q0+64, n0:n0+64] = P . v  (P: [b][1024][2048] bf16, vt: [b][512][2048] bf16)
__launch_bounds__(256)
__global__ void pv_kernel(const __bf16* __restrict__ P, const __bf16* __restrict__ vt,
                          float* __restrict__ out) {
    __shared__ __bf16 Pt[64][40], Vt[64][40];
    const int tid = threadIdx.x;
    const int wave = tid >> 6, lane = tid & 63;
    const int quad = lane >> 4, m16 = lane & 15;
    const int n0 = blockIdx.x * 64, q0 = blockIdx.y * 64, b = blockIdx.z;

    f32x4 acc[4];
#pragma unroll
    for (int nt = 0; nt < 4; ++nt) acc[nt] = (f32x4){0.f, 0.f, 0.f, 0.f};

    const int r = tid >> 2, u = (tid & 3) * 8;
    const __bf16* pp = P + ((size_t)b * 1024 + q0 + r) * 2048 + u;
    const __bf16* vp = vt + ((size_t)b * 512 + n0 + r) * 2048 + u;

    for (int ks = 0; ks < 64; ++ks) {
        __syncthreads();
        *(bf16x8*)&Pt[r][u] = *(const bf16x8*)(pp + ks * 32);
        *(bf16x8*)&Vt[r][u] = *(const bf16x8*)(vp + ks * 32);
        __syncthreads();
        bf16x8 a = *(const bf16x8*)&Pt[wave * 16 + m16][quad * 8];
#pragma unroll
        for (int nt = 0; nt < 4; ++nt) {
            bf16x8 bfr = *(const bf16x8*)&Vt[nt * 16 + m16][quad * 8];
            acc[nt] = MFMA16(a, bfr, acc[nt]);
        }
    }

#pragma unroll
    for (int nt = 0; nt < 4; ++nt) {
#pragma unroll
        for (int rr = 0; rr < 4; ++rr) {
            out[((size_t)b * 1024 + q0 + wave * 16 + quad * 4 + rr) * 512 + n0 + nt * 16 + m16] =
                acc[nt][rr];
        }
    }
}

extern "C" void kernel_launch(void* const* d_in, const int* in_sizes, int n_in,
                              void* d_out, int out_size, void* d_ws, size_t ws_size,
                              hipStream_t stream) {
    const float* enc = (const float*)d_in[0];  // [8,2048,512]
    const float* dec = (const float*)d_in[1];  // [8,1024,512]
    const float* Wq = (const float*)d_in[2];   // [512,512]
    const float* Wk = (const float*)d_in[3];
    const float* Wv = (const float*)d_in[4];
    float* out = (float*)d_out;                // [8,1024,512]

    char* ws = (char*)d_ws;
    __bf16* qh = (__bf16*)(ws + (size_t)0);
    __bf16* ql = (__bf16*)(ws + ((size_t)8 << 20));
    __bf16* kh = (__bf16*)(ws + ((size_t)16 << 20));
    __bf16* kl = (__bf16*)(ws + ((size_t)32 << 20));
    __bf16* vt = (__bf16*)(ws + ((size_t)48 << 20));
    float* S   = (float*)(ws + ((size_t)64 << 20));
    __bf16* P  = (__bf16*)(ws + ((size_t)16 << 20));  // aliases kh/kl (dead after score)

    dim3 blk(256);
    proj_kernel<0><<<dim3(8, 128), blk, 0, stream>>>(dec, Wq, qh, ql);   // q: 8192 rows
    proj_kernel<0><<<dim3(8, 256), blk, 0, stream>>>(enc, Wk, kh, kl);   // k: 16384 rows
    proj_kernel<1><<<dim3(8, 256), blk, 0, stream>>>(enc, Wv, vt, nullptr); // v transposed
    score_kernel<<<dim3(32, 16, 8), blk, 0, stream>>>(qh, ql, kh, kl, S);
    softmax_kernel<<<8192, blk, 0, stream>>>(S, P);
    pv_kernel<<<dim3(8, 16, 8), blk, 0, stream>>>(P, vt, out);
}

// Round 2
// 314.311 us; speedup vs baseline: 1.5005x; 1.5005x over previous
//
#include <hip/hip_runtime.h>
#include <hip/hip_bf16.h>

// Cross-attention B=8, S_ENC=2048, S_DEC=1024, D=512, U=512.
// Phase 1: convert (enc/dec -> split bf16 hi/lo planes; W -> transposed split planes).
// Phase 2: m97-style 128x128-tile GEMMs, BK=32, global_load_lds(16) staging,
//          ds_read_b128 fragments, 16x16x32 bf16 MFMA.
//   q/k proj + score: split-bf16 3-MFMA fp32 emulation (softmax amplifies logit err).
//   v proj + PV: plain bf16 (error budget allows; round-1 absmax 0.031 vs 0.0975).
//
// ws layout (exactly <=128 MiB, with aliasing):
//   [0,16M)   ench      [16M,32M) encl
//   [32M,40M) dech      [40M,48M) decl
//   [48M,51M) Wt planes (Wq hi,lo | Wk hi,lo | Wv hi,lo ; 0.5 MiB each)
//   [0,64M)   S fp32 (aliases convert region; dead by score time)
//   [64M,72M) qh  [72M,80M) ql  [80M,96M) kh  [96M,112M) kl  [112M,128M) vt
//   [64M,80M) P bf16 (aliases qh/ql; dead after score)

typedef __attribute__((ext_vector_type(8))) __bf16 bf16x8;
typedef __attribute__((ext_vector_type(4))) __bf16 bf16x4;
typedef __attribute__((ext_vector_type(4))) float f32x4;

#define MFMA16(a, b, c) __builtin_amdgcn_mfma_f32_16x16x32_bf16(a, b, c, 0, 0, 0)

__device__ __forceinline__ void glds16(const void* g, void* l) {
    __builtin_amdgcn_global_load_lds(
        (const __attribute__((address_space(1))) void*)g,
        (__attribute__((address_space(3))) void*)l, 16, 0, 0);
}

// x fp32[N] -> hi, lo bf16 planes. 8 elems/thread.
__global__ __launch_bounds__(256) void split_convert(const float* __restrict__ x,
                                                     __bf16* __restrict__ hi,
                                                     __bf16* __restrict__ lo) {
    size_t i = ((size_t)blockIdx.x * 256 + threadIdx.x) * 8;
    float4 a0 = *(const float4*)(x + i);
    float4 a1 = *(const float4*)(x + i + 4);
    float v[8] = {a0.x, a0.y, a0.z, a0.w, a1.x, a1.y, a1.z, a1.w};
    bf16x8 h, l;
#pragma unroll
    for (int j = 0; j < 8; ++j) {
        __bf16 hb = (__bf16)v[j];
        h[j] = hb;
        l[j] = (__bf16)(v[j] - (float)hb);
    }
    *(bf16x8*)(hi + i) = h;
    *(bf16x8*)(lo + i) = l;
}

// W[512][512] (z selects Wq/Wk/Wv) -> Wt hi/lo planes [u][d].
__global__ __launch_bounds__(256) void wsplit_kernel(const float* __restrict__ Wq,
                                                     const float* __restrict__ Wk,
                                                     const float* __restrict__ Wv,
                                                     __bf16* __restrict__ planes) {
    const float* W = blockIdx.z == 0 ? Wq : (blockIdx.z == 1 ? Wk : Wv);
    __bf16* hi = planes + (size_t)blockIdx.z * 2 * 262144;
    __bf16* lo = hi + 262144;
    __shared__ float T[64][65];
    const int d0 = blockIdx.y * 64, u0 = blockIdx.x * 64;
    const int tr = threadIdx.x >> 4, tc = (threadIdx.x & 15) * 4;
#pragma unroll
    for (int j = 0; j < 4; ++j) {
        float4 vv = *(const float4*)(W + (size_t)(d0 + tr + j * 16) * 512 + u0 + tc);
        T[tr + j * 16][tc + 0] = vv.x;
        T[tr + j * 16][tc + 1] = vv.y;
        T[tr + j * 16][tc + 2] = vv.z;
        T[tr + j * 16][tc + 3] = vv.w;
    }
    __syncthreads();
#pragma unroll
    for (int j = 0; j < 4; ++j) {
        int ul = tr + j * 16;
        bf16x4 h, l;
#pragma unroll
        for (int i = 0; i < 4; ++i) {
            float x = T[tc + i][ul];
            __bf16 hb = (__bf16)x;
            h[i] = hb;
            l[i] = (__bf16)(x - (float)hb);
        }
        *(bf16x4*)(hi + (size_t)(u0 + ul) * 512 + d0 + tc) = h;
        *(bf16x4*)(lo + (size_t)(u0 + ul) * 512 + d0 + tc) = l;
    }
}

// Unified 128x128-tile GEMM, C[m][n] = sum_k A[m][k] * B[n][k].
// SPLIT: 3-MFMA hi/lo fp32 emulation. OUT: 0 = split bf16 (O1 hi, O2 lo),
// 1 = transposed bf16 (vt[b][u][s], via LDS transpose), 2 = fp32.
template <bool SPLIT, int OUT>
__global__ __launch_bounds__(256) void gemm_kernel(
    const __bf16* __restrict__ Ah, const __bf16* __restrict__ Al,
    const __bf16* __restrict__ Bh, const __bf16* __restrict__ Bl,
    void* __restrict__ O1, void* __restrict__ O2,
    int lda, int ldb, int K, int a_row_batch, long b_batch, int ldo) {
    __shared__ __align__(16) char smem[SPLIT ? 32768 : 16384];
    __bf16* sAh = (__bf16*)smem;
    __bf16* sAl = (__bf16*)(smem + 8192);
    __bf16* sBh = (__bf16*)(smem + (SPLIT ? 16384 : 8192));
    __bf16* sBl = (__bf16*)(smem + 24576);

    const int tid = threadIdx.x;
    const int wave = tid >> 6, lane = tid & 63;
    const int quad = lane >> 4, m16 = lane & 15;
    const int wr = wave >> 1, wc = wave & 1;
    const int z = blockIdx.z;
    const int row0 = z * a_row_batch + blockIdx.y * 128;
    const int col0 = blockIdx.x * 128;

    const __bf16* Bhz = Bh + (size_t)z * b_batch;

    // Staging: tile [128][32] bf16 row-major (64 B rows), wave w instr j covers
    // rows (w*2+j)*16 + lane/4, 16 B per lane (global_load_lds: lds = base + lane*16).
    const int srow = wave * 32 + (lane >> 2);
    const int scol = (lane & 3) * 8;
    const __bf16* agp = Ah + (size_t)(row0 + srow) * lda + scol;
    const __bf16* bgp = Bhz + (size_t)(col0 + srow) * ldb + scol;
    const __bf16* alp = SPLIT ? Al + (size_t)(row0 + srow) * lda + scol : nullptr;
    const __bf16* blp = SPLIT ? Bl + (size_t)z * b_batch + (size_t)(col0 + srow) * ldb + scol
                              : nullptr;
    char* ldsA = smem + wave * 2048;
    char* ldsB = (char*)sBh + wave * 2048;
    char* ldsAl = (char*)sAl + wave * 2048;
    char* ldsBl = (char*)sBl + wave * 2048;

    f32x4 acc[4][4];
#pragma unroll
    for (int mt = 0; mt < 4; ++mt)
#pragma unroll
        for (int nt = 0; nt < 4; ++nt) acc[mt][nt] = (f32x4){0.f, 0.f, 0.f, 0.f};

    for (int k0 = 0; k0 < K; k0 += 32) {
        __syncthreads();
#pragma unroll
        for (int j = 0; j < 2; ++j) {
            glds16(agp + k0 + j * 16 * lda, ldsA + j * 1024);
            glds16(bgp + k0 + j * 16 * ldb, ldsB + j * 1024);
            if (SPLIT) {
                glds16(alp + k0 + j * 16 * lda, ldsAl + j * 1024);
                glds16(blp + k0 + j * 16 * ldb, ldsBl + j * 1024);
            }
        }
        __syncthreads();

        const char* pa = (const char*)sAh + (wr * 64 + m16) * 64 + quad * 16;
        const char* pal = (const char*)sAl + (wr * 64 + m16) * 64 + quad * 16;
        const char* pb = (const char*)sBh + (wc * 64 + m16) * 64 + quad * 16;
        const char* pbl = (const char*)sBl + (wc * 64 + m16) * 64 + quad * 16;

        bf16x8 ah[4], al[4];
#pragma unroll
        for (int mt = 0; mt < 4; ++mt) {
            ah[mt] = *(const bf16x8*)(pa + mt * 1024);
            if (SPLIT) al[mt] = *(const bf16x8*)(pal + mt * 1024);
        }
#pragma unroll
        for (int nt = 0; nt < 4; ++nt) {
            bf16x8 bh = *(const bf16x8*)(pb + nt * 1024);
            bf16x8 bl;
            if (SPLIT) bl = *(const bf16x8*)(pbl + nt * 1024);
#pragma unroll
            for (int mt = 0; mt < 4; ++mt) {
                acc[mt][nt] = MFMA16(ah[mt], bh, acc[mt][nt]);
                if (SPLIT) {
                    acc[mt][nt] = MFMA16(ah[mt], bl, acc[mt][nt]);
                    acc[mt][nt] = MFMA16(al[mt], bh, acc[mt][nt]);
                }
            }
        }
    }

    if (OUT == 0) {
        __bf16* oh = (__bf16*)O1;
        __bf16* ol = (__bf16*)O2;
#pragma unroll
        for (int mt = 0; mt < 4; ++mt)
#pragma unroll
            for (int nt = 0; nt < 4; ++nt)
#pragma unroll
                for (int rr = 0; rr < 4; ++rr) {
                    int row = row0 + wr * 64 + mt * 16 + quad * 4 + rr;
                    int col = col0 + wc * 64 + nt * 16 + m16;
                    float x = acc[mt][nt][rr];
                    __bf16 h = (__bf16)x;
                    oh[(size_t)row * ldo + col] = h;
                    ol[(size_t)row * ldo + col] = (__bf16)(x - (float)h);
                }
    } else if (OUT == 2) {
        float* o = (float*)O1;
#pragma unroll
        for (int mt = 0; mt < 4; ++mt)
#pragma unroll
            for (int nt = 0; nt < 4; ++nt)
#pragma unroll
                for (int rr = 0; rr < 4; ++rr) {
                    int row = row0 + wr * 64 + mt * 16 + quad * 4 + rr;
                    int col = col0 + wc * 64 + nt * 16 + m16;
                    o[(size_t)row * ldo + col] = acc[mt][nt][rr];
                }
    } else {
        // OUT == 1: write C^T as bf16 into vt[b][u][s], coalesced via per-wave
        // LDS transpose region (4 KB/wave, two passes of 32 n's).
        __bf16* vt = (__bf16*)O1;
        const int row0g = blockIdx.y * 128;
        const int b = row0g >> 11;
        const int s_base = (row0g & 2047) + wr * 64;
        char* reg = smem + wave * 4096;
#pragma unroll
        for (int p = 0; p < 2; ++p) {
            __syncthreads();
#pragma unroll
            for (int nt2 = 0; nt2 < 2; ++nt2) {
                int nt = p * 2 + nt2;
#pragma unroll
                for (int mt = 0; mt < 4; ++mt) {
                    bf16x4 pk;
#pragma unroll
                    for (int rr = 0; rr < 4; ++rr) pk[rr] = (__bf16)acc[mt][nt][rr];
                    *(bf16x4*)(reg + (nt2 * 16 + m16) * 128 + (mt * 16 + quad * 4) * 2) = pk;
                }
            }
            __syncthreads();
            const int u_base = col0 + wc * 64 + p * 32;
#pragma unroll
            for (int j = 0; j < 4; ++j) {
                int n = j * 8 + (lane >> 3);
                int mo = (lane & 7) * 8;
                bf16x8 val = *(const bf16x8*)(reg + n * 128 + mo * 2);
                *(bf16x8*)(vt + (size_t)(b * 512 + u_base + n) * 2048 + s_base + mo) = val;
            }
        }
    }
}

// Row softmax over 2048 cols, fp32 in -> bf16 out. One block per row.
__global__ __launch_bounds__(256) void softmax_kernel(const float* __restrict__ S,
                                                      __bf16* __restrict__ P) {
    const int row = blockIdx.x;
    const int tid = threadIdx.x;
    const int wave = tid >> 6, lane = tid & 63;
    __shared__ float red[8];

    const float* sp = S + (size_t)row * 2048 + tid * 8;
    float4 x0 = *(const float4*)sp;
    float4 x1 = *(const float4*)(sp + 4);
    float v[8] = {x0.x, x0.y, x0.z, x0.w, x1.x, x1.y, x1.z, x1.w};

    float mx = v[0];
#pragma unroll
    for (int i = 1; i < 8; ++i) mx = fmaxf(mx, v[i]);
#pragma unroll
    for (int off = 32; off > 0; off >>= 1) mx = fmaxf(mx, __shfl_down(mx, off));
    if (lane == 0) red[wave] = mx;
    __syncthreads();
    if (tid == 0) red[4] = fmaxf(fmaxf(red[0], red[1]), fmaxf(red[2], red[3]));
    __syncthreads();
    mx = red[4];

    float e[8];
    float sum = 0.f;
#pragma unroll
    for (int i = 0; i < 8; ++i) {
        e[i] = exp2f((v[i] - mx) * 1.44269504088896f);
        sum += e[i];
    }
#pragma unroll
    for (int off = 32; off > 0; off >>= 1) sum += __shfl_down(sum, off);
    if (lane == 0) red[wave] = sum;
    __syncthreads();
    if (tid == 0) red[5] = red[0] + red[1] + red[2] + red[3];
    __syncthreads();
    float inv = 1.0f / red[5];

    bf16x8 ov;
#pragma unroll
    for (int i = 0; i < 8; ++i) ov[i] = (__bf16)(e[i] * inv);
    *(bf16x8*)(P + (size_t)row * 2048 + tid * 8) = ov;
}

extern "C" void kernel_launch(void* const* d_in, const int* in_sizes, int n_in,
                              void* d_out, int out_size, void* d_ws, size_t ws_size,
                              hipStream_t stream) {
    const float* enc = (const float*)d_in[0];  // [8,2048,512]
    const float* dec = (const float*)d_in[1];  // [8,1024,512]
    const float* Wq = (const float*)d_in[2];   // [512,512]
    const float* Wk = (const float*)d_in[3];
    const float* Wv = (const float*)d_in[4];
    float* out = (float*)d_out;                // [8,1024,512] fp32

    char* ws = (char*)d_ws;
    __bf16* ench = (__bf16*)(ws);
    __bf16* encl = (__bf16*)(ws + ((size_t)16 << 20));
    __bf16* dech = (__bf16*)(ws + ((size_t)32 << 20));
    __bf16* decl_ = (__bf16*)(ws + ((size_t)40 << 20));
    __bf16* wts = (__bf16*)(ws + ((size_t)48 << 20));  // 6 planes x 262144 elems
    float* S = (float*)(ws);                           // aliases convert region
    __bf16* qh = (__bf16*)(ws + ((size_t)64 << 20));
    __bf16* ql = (__bf16*)(ws + ((size_t)72 << 20));
    __bf16* kh = (__bf16*)(ws + ((size_t)80 << 20));
    __bf16* kl = (__bf16*)(ws + ((size_t)96 << 20));
    __bf16* vt = (__bf16*)(ws + ((size_t)112 << 20));
    __bf16* P = (__bf16*)(ws + ((size_t)64 << 20));    // aliases qh/ql

    dim3 blk(256);
    // Phase 1: convert
    split_convert<<<4096, blk, 0, stream>>>(enc, ench, encl);
    split_convert<<<2048, blk, 0, stream>>>(dec, dech, decl_);
    wsplit_kernel<<<dim3(8, 8, 3), blk, 0, stream>>>(Wq, Wk, Wv, wts);
    // Phase 2: projections
    gemm_kernel<true, 0><<<dim3(4, 64, 1), blk, 0, stream>>>(
        dech, decl_, wts, wts + 262144, qh, ql, 512, 512, 512, 0, 0, 512);
    gemm_kernel<true, 0><<<dim3(4, 128, 1), blk, 0, stream>>>(
        ench, encl, wts + 524288, wts + 786432, kh, kl, 512, 512, 512, 0, 0, 512);
    gemm_kernel<false, 1><<<dim3(4, 128, 1), blk, 0, stream>>>(
        ench, nullptr, wts + 1048576, nullptr, vt, nullptr, 512, 512, 512, 0, 0, 0);
    // Score: S[b,q,s] = q . k^T (split)
    gemm_kernel<true, 2><<<dim3(16, 8, 8), blk, 0, stream>>>(
        qh, ql, kh, kl, S, nullptr, 512, 512, 512, 1024, (long)2048 * 512, 2048);
    softmax_kernel<<<8192, blk, 0, stream>>>(S, P);
    // PV: out[b,q,u] = P . V
    gemm_kernel<false, 2><<<dim3(4, 8, 8), blk, 0, stream>>>(
        P, nullptr, vt, nullptr, out, nullptr, 2048, 2048, 2048, 1024, (long)512 * 2048, 512);
}

// Round 3
// 249.286 us; speedup vs baseline: 1.8919x; 1.2608x over previous
//
#include <hip/hip_runtime.h>
#include <hip/hip_bf16.h>

// Cross-attention B=8, S_ENC=2048, S_DEC=1024, D=512, U=512.
// All-fp16 single-MFMA pipeline (v_mfma_f32_16x16x32_f16, fp32 accum).
// Rationale: unscaled logits ~N(0,22.6) => softmax is near-one-hot; logit
// noise sigma~8e-3 from fp16 rounding contributes only ~0.02 absmax (near-tie
// rows), while fp16 v/P cuts the old bf16 PV error (0.031) by 8x.
// MFMA work: 55.9 G (was 116 G bf16-split). m97-style 128x128 tiles, BK=32,
// global_load_lds(16), ds_read_b128 fragments.
//
// ws layout (aliased, <=128 MiB):
//   qh   [0,8M)     fp16 [8192][512]     (dead after score)
//   kh   [8M,24M)   fp16 [16384][512]    (dead after score)
//   P    [0,32M)    fp16 [8192][2048]    (written by softmax)
//   vt   [32M,48M)  fp16 [8][512][2048]
//   S    [48M,112M) fp32 [8192][2048]
//   dech [48M,56M)  fp16 (dead after q proj, before S written)
//   Wt   [56M,58M)  fp16 3 planes [512][512] (dead after v proj)
//   ench [112M,128M) fp16 (dead after v proj)

typedef __attribute__((ext_vector_type(8))) _Float16 f16x8;
typedef __attribute__((ext_vector_type(4))) _Float16 f16x4;
typedef __attribute__((ext_vector_type(4))) float f32x4;

#define MFMA16(a, b, c) __builtin_amdgcn_mfma_f32_16x16x32_f16(a, b, c, 0, 0, 0)

__device__ __forceinline__ void glds16(const void* g, void* l) {
    __builtin_amdgcn_global_load_lds(
        (const __attribute__((address_space(1))) void*)g,
        (__attribute__((address_space(3))) void*)l, 16, 0, 0);
}

// fp32[N] -> fp16[N], 8 elems/thread.
__global__ __launch_bounds__(256) void convert_f16(const float* __restrict__ x,
                                                   _Float16* __restrict__ o) {
    size_t i = ((size_t)blockIdx.x * 256 + threadIdx.x) * 8;
    float4 a0 = *(const float4*)(x + i);
    float4 a1 = *(const float4*)(x + i + 4);
    float v[8] = {a0.x, a0.y, a0.z, a0.w, a1.x, a1.y, a1.z, a1.w};
    f16x8 h;
#pragma unroll
    for (int j = 0; j < 8; ++j) h[j] = (_Float16)v[j];
    *(f16x8*)(o + i) = h;
}

// W[512][512] (z selects Wq/Wk/Wv) -> Wt fp16 plane [u][d].
__global__ __launch_bounds__(256) void wtrans_kernel(const float* __restrict__ Wq,
                                                     const float* __restrict__ Wk,
                                                     const float* __restrict__ Wv,
                                                     _Float16* __restrict__ planes) {
    const float* W = blockIdx.z == 0 ? Wq : (blockIdx.z == 1 ? Wk : Wv);
    _Float16* ot = planes + (size_t)blockIdx.z * 262144;
    __shared__ float T[64][65];
    const int d0 = blockIdx.y * 64, u0 = blockIdx.x * 64;
    const int tr = threadIdx.x >> 4, tc = (threadIdx.x & 15) * 4;
#pragma unroll
    for (int j = 0; j < 4; ++j) {
        float4 vv = *(const float4*)(W + (size_t)(d0 + tr + j * 16) * 512 + u0 + tc);
        T[tr + j * 16][tc + 0] = vv.x;
        T[tr + j * 16][tc + 1] = vv.y;
        T[tr + j * 16][tc + 2] = vv.z;
        T[tr + j * 16][tc + 3] = vv.w;
    }
    __syncthreads();
#pragma unroll
    for (int j = 0; j < 4; ++j) {
        int ul = tr + j * 16;
        f16x4 h;
#pragma unroll
        for (int i = 0; i < 4; ++i) h[i] = (_Float16)T[tc + i][ul];
        *(f16x4*)(ot + (size_t)(u0 + ul) * 512 + d0 + tc) = h;
    }
}

// 128x128-tile GEMM, C[m][n] = sum_k A[m][k] * B[n][k]  (fp16 in, fp32 accum).
// OUT: 0 = fp16 C, 1 = transposed fp16 (vt[b][u][s] via LDS transpose), 2 = fp32 C.
template <int OUT>
__global__ __launch_bounds__(256) void gemm_kernel(
    const _Float16* __restrict__ A, const _Float16* __restrict__ B,
    void* __restrict__ O1,
    int lda, int ldb, int K, int a_row_batch, long b_batch, int ldo) {
    __shared__ __align__(16) char smem[16384];
    _Float16* sA = (_Float16*)smem;
    _Float16* sB = (_Float16*)(smem + 8192);

    const int tid = threadIdx.x;
    const int wave = tid >> 6, lane = tid & 63;
    const int quad = lane >> 4, m16 = lane & 15;
    const int wr = wave >> 1, wc = wave & 1;
    const int z = blockIdx.z;
    const int row0 = z * a_row_batch + blockIdx.y * 128;
    const int col0 = blockIdx.x * 128;

    // Staging: tile [128][32] fp16 row-major (64 B rows); wave w instr j covers
    // rows (w*2+j)*16 + lane/4, 16 B per lane (glds: lds = base + lane*16).
    const int srow = wave * 32 + (lane >> 2);
    const int scol = (lane & 3) * 8;
    const _Float16* agp = A + (size_t)(row0 + srow) * lda + scol;
    const _Float16* bgp = B + (size_t)z * b_batch + (size_t)(col0 + srow) * ldb + scol;
    char* ldsA = smem + wave * 2048;
    char* ldsB = (char*)sB + wave * 2048;

    f32x4 acc[4][4];
#pragma unroll
    for (int mt = 0; mt < 4; ++mt)
#pragma unroll
        for (int nt = 0; nt < 4; ++nt) acc[mt][nt] = (f32x4){0.f, 0.f, 0.f, 0.f};

    for (int k0 = 0; k0 < K; k0 += 32) {
        __syncthreads();
#pragma unroll
        for (int j = 0; j < 2; ++j) {
            glds16(agp + k0 + j * 16 * lda, ldsA + j * 1024);
            glds16(bgp + k0 + j * 16 * ldb, ldsB + j * 1024);
        }
        __syncthreads();

        const char* pa = (const char*)sA + (wr * 64 + m16) * 64 + quad * 16;
        const char* pb = (const char*)sB + (wc * 64 + m16) * 64 + quad * 16;

        f16x8 af[4];
#pragma unroll
        for (int mt = 0; mt < 4; ++mt) af[mt] = *(const f16x8*)(pa + mt * 1024);
#pragma unroll
        for (int nt = 0; nt < 4; ++nt) {
            f16x8 bf = *(const f16x8*)(pb + nt * 1024);
#pragma unroll
            for (int mt = 0; mt < 4; ++mt) acc[mt][nt] = MFMA16(af[mt], bf, acc[mt][nt]);
        }
    }

    if (OUT == 0) {
        _Float16* o = (_Float16*)O1;
#pragma unroll
        for (int mt = 0; mt < 4; ++mt)
#pragma unroll
            for (int nt = 0; nt < 4; ++nt)
#pragma unroll
                for (int rr = 0; rr < 4; ++rr) {
                    int row = row0 + wr * 64 + mt * 16 + quad * 4 + rr;
                    int col = col0 + wc * 64 + nt * 16 + m16;
                    o[(size_t)row * ldo + col] = (_Float16)acc[mt][nt][rr];
                }
    } else if (OUT == 2) {
        float* o = (float*)O1;
#pragma unroll
        for (int mt = 0; mt < 4; ++mt)
#pragma unroll
            for (int nt = 0; nt < 4; ++nt)
#pragma unroll
                for (int rr = 0; rr < 4; ++rr) {
                    int row = row0 + wr * 64 + mt * 16 + quad * 4 + rr;
                    int col = col0 + wc * 64 + nt * 16 + m16;
                    o[(size_t)row * ldo + col] = acc[mt][nt][rr];
                }
    } else {
        // OUT == 1: write C^T fp16 into vt[b][u][s], coalesced via per-wave
        // LDS transpose region (4 KB/wave, two passes of 32 n's).
        _Float16* vt = (_Float16*)O1;
        const int row0g = blockIdx.y * 128;
        const int b = row0g >> 11;
        const int s_base = (row0g & 2047) + wr * 64;
        char* reg = smem + wave * 4096;
#pragma unroll
        for (int p = 0; p < 2; ++p) {
            __syncthreads();
#pragma unroll
            for (int nt2 = 0; nt2 < 2; ++nt2) {
                int nt = p * 2 + nt2;
#pragma unroll
                for (int mt = 0; mt < 4; ++mt) {
                    f16x4 pk;
#pragma unroll
                    for (int rr = 0; rr < 4; ++rr) pk[rr] = (_Float16)acc[mt][nt][rr];
                    *(f16x4*)(reg + (nt2 * 16 + m16) * 128 + (mt * 16 + quad * 4) * 2) = pk;
                }
            }
            __syncthreads();
            const int u_base = col0 + wc * 64 + p * 32;
#pragma unroll
            for (int j = 0; j < 4; ++j) {
                int n = j * 8 + (lane >> 3);
                int mo = (lane & 7) * 8;
                f16x8 val = *(const f16x8*)(reg + n * 128 + mo * 2);
                *(f16x8*)(vt + (size_t)(b * 512 + u_base + n) * 2048 + s_base + mo) = val;
            }
        }
    }
}

// Row softmax over 2048 cols, fp32 in -> fp16 out. One block per row.
__global__ __launch_bounds__(256) void softmax_kernel(const float* __restrict__ S,
                                                      _Float16* __restrict__ P) {
    const int row = blockIdx.x;
    const int tid = threadIdx.x;
    const int wave = tid >> 6, lane = tid & 63;
    __shared__ float red[8];

    const float* sp = S + (size_t)row * 2048 + tid * 8;
    float4 x0 = *(const float4*)sp;
    float4 x1 = *(const float4*)(sp + 4);
    float v[8] = {x0.x, x0.y, x0.z, x0.w, x1.x, x1.y, x1.z, x1.w};

    float mx = v[0];
#pragma unroll
    for (int i = 1; i < 8; ++i) mx = fmaxf(mx, v[i]);
#pragma unroll
    for (int off = 32; off > 0; off >>= 1) mx = fmaxf(mx, __shfl_down(mx, off));
    if (lane == 0) red[wave] = mx;
    __syncthreads();
    if (tid == 0) red[4] = fmaxf(fmaxf(red[0], red[1]), fmaxf(red[2], red[3]));
    __syncthreads();
    mx = red[4];

    float e[8];
    float sum = 0.f;
#pragma unroll
    for (int i = 0; i < 8; ++i) {
        e[i] = exp2f((v[i] - mx) * 1.44269504088896f);
        sum += e[i];
    }
#pragma unroll
    for (int off = 32; off > 0; off >>= 1) sum += __shfl_down(sum, off);
    if (lane == 0) red[wave] = sum;
    __syncthreads();
    if (tid == 0) red[5] = red[0] + red[1] + red[2] + red[3];
    __syncthreads();
    float inv = 1.0f / red[5];

    f16x8 ov;
#pragma unroll
    for (int i = 0; i < 8; ++i) ov[i] = (_Float16)(e[i] * inv);
    *(f16x8*)(P + (size_t)row * 2048 + tid * 8) = ov;
}

extern "C" void kernel_launch(void* const* d_in, const int* in_sizes, int n_in,
                              void* d_out, int out_size, void* d_ws, size_t ws_size,
                              hipStream_t stream) {
    const float* enc = (const float*)d_in[0];  // [8,2048,512]
    const float* dec = (const float*)d_in[1];  // [8,1024,512]
    const float* Wq = (const float*)d_in[2];   // [512,512]
    const float* Wk = (const float*)d_in[3];
    const float* Wv = (const float*)d_in[4];
    float* out = (float*)d_out;                // [8,1024,512] fp32

    char* ws = (char*)d_ws;
    _Float16* qh = (_Float16*)(ws);
    _Float16* kh = (_Float16*)(ws + ((size_t)8 << 20));
    _Float16* P = (_Float16*)(ws);                       // aliases qh/kh after score
    _Float16* vt = (_Float16*)(ws + ((size_t)32 << 20));
    float* S = (float*)(ws + ((size_t)48 << 20));
    _Float16* dech = (_Float16*)(ws + ((size_t)48 << 20));  // dead before S written
    _Float16* wts = (_Float16*)(ws + ((size_t)56 << 20));   // dead before S written
    _Float16* ench = (_Float16*)(ws + ((size_t)112 << 20));

    dim3 blk(256);
    convert_f16<<<4096, blk, 0, stream>>>(enc, ench);
    convert_f16<<<2048, blk, 0, stream>>>(dec, dech);
    wtrans_kernel<<<dim3(8, 8, 3), blk, 0, stream>>>(Wq, Wk, Wv, wts);
    // Projections (single fp16 MFMA each)
    gemm_kernel<0><<<dim3(4, 64, 1), blk, 0, stream>>>(
        dech, wts, qh, 512, 512, 512, 0, 0, 512);
    gemm_kernel<0><<<dim3(4, 128, 1), blk, 0, stream>>>(
        ench, wts + 262144, kh, 512, 512, 512, 0, 0, 512);
    gemm_kernel<1><<<dim3(4, 128, 1), blk, 0, stream>>>(
        ench, wts + 524288, vt, 512, 512, 512, 0, 0, 0);
    // Score: S[b,q,s] = q . k^T
    gemm_kernel<2><<<dim3(16, 8, 8), blk, 0, stream>>>(
        qh, kh, S, 512, 512, 512, 1024, (long)2048 * 512, 2048);
    softmax_kernel<<<8192, blk, 0, stream>>>(S, P);
    // PV: out[b,q,u] = P . V
    gemm_kernel<2><<<dim3(4, 8, 8), blk, 0, stream>>>(
        P, vt, out, 2048, 2048, 2048, 1024, (long)512 * 2048, 512);
}

// Round 4
// 233.113 us; speedup vs baseline: 2.0232x; 1.0694x over previous
//
#include <hip/hip_runtime.h>
#include <hip/hip_bf16.h>

// Cross-attention B=8, S_ENC=2048, S_DEC=1024, D=512, U=512.
// All-fp16 single-MFMA pipeline (v_mfma_f32_16x16x32_f16, fp32 accum).
// R4: double-buffered K-loop (1 barrier/iter, prefetch overlaps MFMA) +
// BM=64 tile variant for the low-block-count GEMMs (PV: 256->512 blocks,
// q-proj: 256->512). PV was 50us at 9% occupancy / 12% MfmaUtil (1 block/CU,
// fully exposed vmcnt-drain before barrier).
//
// ws layout (aliased, <=128 MiB):
//   qh   [0,8M)     fp16 [8192][512]     (dead after score)
//   kh   [8M,24M)   fp16 [16384][512]    (dead after score)
//   P    [0,32M)    fp16 [8192][2048]    (written by softmax)
//   vt   [32M,48M)  fp16 [8][512][2048]
//   S    [48M,112M) fp32 [8192][2048]
//   dech [48M,56M)  fp16 (dead after q proj, before S written)
//   Wt   [56M,58M)  fp16 3 planes [512][512] (dead after v proj)
//   ench [112M,128M) fp16 (dead after v proj)

typedef __attribute__((ext_vector_type(8))) _Float16 f16x8;
typedef __attribute__((ext_vector_type(4))) _Float16 f16x4;
typedef __attribute__((ext_vector_type(4))) float f32x4;

#define MFMA16(a, b, c) __builtin_amdgcn_mfma_f32_16x16x32_f16(a, b, c, 0, 0, 0)

__device__ __forceinline__ void glds16(const void* g, void* l) {
    __builtin_amdgcn_global_load_lds(
        (const __attribute__((address_space(1))) void*)g,
        (__attribute__((address_space(3))) void*)l, 16, 0, 0);
}

// fp32[N] -> fp16[N], 8 elems/thread.
__global__ __launch_bounds__(256) void convert_f16(const float* __restrict__ x,
                                                   _Float16* __restrict__ o) {
    size_t i = ((size_t)blockIdx.x * 256 + threadIdx.x) * 8;
    float4 a0 = *(const float4*)(x + i);
    float4 a1 = *(const float4*)(x + i + 4);
    float v[8] = {a0.x, a0.y, a0.z, a0.w, a1.x, a1.y, a1.z, a1.w};
    f16x8 h;
#pragma unroll
    for (int j = 0; j < 8; ++j) h[j] = (_Float16)v[j];
    *(f16x8*)(o + i) = h;
}

// W[512][512] (z selects Wq/Wk/Wv) -> Wt fp16 plane [u][d].
__global__ __launch_bounds__(256) void wtrans_kernel(const float* __restrict__ Wq,
                                                     const float* __restrict__ Wk,
                                                     const float* __restrict__ Wv,
                                                     _Float16* __restrict__ planes) {
    const float* W = blockIdx.z == 0 ? Wq : (blockIdx.z == 1 ? Wk : Wv);
    _Float16* ot = planes + (size_t)blockIdx.z * 262144;
    __shared__ float T[64][65];
    const int d0 = blockIdx.y * 64, u0 = blockIdx.x * 64;
    const int tr = threadIdx.x >> 4, tc = (threadIdx.x & 15) * 4;
#pragma unroll
    for (int j = 0; j < 4; ++j) {
        float4 vv = *(const float4*)(W + (size_t)(d0 + tr + j * 16) * 512 + u0 + tc);
        T[tr + j * 16][tc + 0] = vv.x;
        T[tr + j * 16][tc + 1] = vv.y;
        T[tr + j * 16][tc + 2] = vv.z;
        T[tr + j * 16][tc + 3] = vv.w;
    }
    __syncthreads();
#pragma unroll
    for (int j = 0; j < 4; ++j) {
        int ul = tr + j * 16;
        f16x4 h;
#pragma unroll
        for (int i = 0; i < 4; ++i) h[i] = (_Float16)T[tc + i][ul];
        *(f16x4*)(ot + (size_t)(u0 + ul) * 512 + d0 + tc) = h;
    }
}

// BM x 128 tile GEMM, C[m][n] = sum_k A[m][k] * B[n][k] (fp16 in, fp32 accum).
// Double-buffered LDS, one barrier per K-iter. 4 waves; wave tile (BM/2)x64.
// OUT: 0 = fp16 C, 1 = transposed fp16 (vt[b][u][s], BM=128 only), 2 = fp32 C.
template <int BM, int OUT>
__global__ __launch_bounds__(256) void gemm_kernel(
    const _Float16* __restrict__ A, const _Float16* __restrict__ B,
    void* __restrict__ O1,
    int lda, int ldb, int K, int a_row_batch, long b_batch, int ldo) {
    constexpr int BUFSZ = BM * 64 + 8192;  // bytes: A tile then B tile
    constexpr int MT = BM / 32;            // m-frags per wave
    constexpr int JA = BM / 64;            // A stage instrs per wave
    __shared__ __align__(16) char smem[2 * BUFSZ];

    const int tid = threadIdx.x;
    const int wave = tid >> 6, lane = tid & 63;
    const int quad = lane >> 4, m16 = lane & 15;
    const int wr = wave >> 1, wc = wave & 1;
    const int z = blockIdx.z;
    const int row0 = z * a_row_batch + blockIdx.y * BM;
    const int col0 = blockIdx.x * 128;

    // Staging addresses: tile rows of 64 B; glds puts lane L at base + L*16.
    const int srowA = wave * (16 * JA) + (lane >> 2);
    const int srowB = wave * 32 + (lane >> 2);
    const int scol = (lane & 3) * 8;
    const _Float16* agp = A + (size_t)(row0 + srowA) * lda + scol;
    const _Float16* bgp = B + (size_t)z * b_batch + (size_t)(col0 + srowB) * ldb + scol;
    const int ldsAoff = wave * (1024 * JA);
    const int ldsBoff = BM * 64 + wave * 2048;

    f32x4 acc[MT][4];
#pragma unroll
    for (int mt = 0; mt < MT; ++mt)
#pragma unroll
        for (int nt = 0; nt < 4; ++nt) acc[mt][nt] = (f32x4){0.f, 0.f, 0.f, 0.f};

    const int nIter = K / 32;
    auto stage = [&](int i, int buf) {
        char* base = smem + buf * BUFSZ;
        const int k0 = i * 32;
#pragma unroll
        for (int j = 0; j < JA; ++j)
            glds16(agp + k0 + j * 16 * lda, base + ldsAoff + j * 1024);
#pragma unroll
        for (int j = 0; j < 2; ++j)
            glds16(bgp + k0 + j * 16 * ldb, base + ldsBoff + j * 1024);
    };

    stage(0, 0);
    for (int i = 0; i < nIter; ++i) {
        __syncthreads();  // compiler emits vmcnt(0) drain: buf[i&1] staged
        if (i + 1 < nIter) stage(i + 1, (i + 1) & 1);
        const char* bb = smem + (i & 1) * BUFSZ;
        const char* pa = bb + (wr * (BM / 2) + m16) * 64 + quad * 16;
        const char* pb = bb + BM * 64 + (wc * 64 + m16) * 64 + quad * 16;
        f16x8 af[MT];
#pragma unroll
        for (int mt = 0; mt < MT; ++mt) af[mt] = *(const f16x8*)(pa + mt * 1024);
#pragma unroll
        for (int nt = 0; nt < 4; ++nt) {
            f16x8 bf = *(const f16x8*)(pb + nt * 1024);
#pragma unroll
            for (int mt = 0; mt < MT; ++mt) acc[mt][nt] = MFMA16(af[mt], bf, acc[mt][nt]);
        }
    }

    if (OUT == 0) {
        _Float16* o = (_Float16*)O1;
#pragma unroll
        for (int mt = 0; mt < MT; ++mt)
#pragma unroll
            for (int nt = 0; nt < 4; ++nt)
#pragma unroll
                for (int rr = 0; rr < 4; ++rr) {
                    int row = row0 + wr * (BM / 2) + mt * 16 + quad * 4 + rr;
                    int col = col0 + wc * 64 + nt * 16 + m16;
                    o[(size_t)row * ldo + col] = (_Float16)acc[mt][nt][rr];
                }
    } else if (OUT == 2) {
        float* o = (float*)O1;
#pragma unroll
        for (int mt = 0; mt < MT; ++mt)
#pragma unroll
            for (int nt = 0; nt < 4; ++nt)
#pragma unroll
                for (int rr = 0; rr < 4; ++rr) {
                    int row = row0 + wr * (BM / 2) + mt * 16 + quad * 4 + rr;
                    int col = col0 + wc * 64 + nt * 16 + m16;
                    o[(size_t)row * ldo + col] = acc[mt][nt][rr];
                }
    } else {
        // OUT == 1 (BM=128 only): write C^T fp16 into vt[b][u][s], coalesced
        // via per-wave LDS transpose region (4 KB/wave, two passes of 32 n's).
        _Float16* vt = (_Float16*)O1;
        const int row0g = blockIdx.y * 128;
        const int b = row0g >> 11;
        const int s_base = (row0g & 2047) + wr * 64;
        char* reg = smem + wave * 4096;
#pragma unroll
        for (int p = 0; p < 2; ++p) {
            __syncthreads();
#pragma unroll
            for (int nt2 = 0; nt2 < 2; ++nt2) {
                int nt = p * 2 + nt2;
#pragma unroll
                for (int mt = 0; mt < 4; ++mt) {
                    f16x4 pk;
#pragma unroll
                    for (int rr = 0; rr < 4; ++rr) pk[rr] = (_Float16)acc[mt][nt][rr];
                    *(f16x4*)(reg + (nt2 * 16 + m16) * 128 + (mt * 16 + quad * 4) * 2) = pk;
                }
            }
            __syncthreads();
            const int u_base = col0 + wc * 64 + p * 32;
#pragma unroll
            for (int j = 0; j < 4; ++j) {
                int n = j * 8 + (lane >> 3);
                int mo = (lane & 7) * 8;
                f16x8 val = *(const f16x8*)(reg + n * 128 + mo * 2);
                *(f16x8*)(vt + (size_t)(b * 512 + u_base + n) * 2048 + s_base + mo) = val;
            }
        }
    }
}

// Row softmax over 2048 cols, fp32 in -> fp16 out. One block per row.
__global__ __launch_bounds__(256) void softmax_kernel(const float* __restrict__ S,
                                                      _Float16* __restrict__ P) {
    const int row = blockIdx.x;
    const int tid = threadIdx.x;
    const int wave = tid >> 6, lane = tid & 63;
    __shared__ float red[8];

    const float* sp = S + (size_t)row * 2048 + tid * 8;
    float4 x0 = *(const float4*)sp;
    float4 x1 = *(const float4*)(sp + 4);
    float v[8] = {x0.x, x0.y, x0.z, x0.w, x1.x, x1.y, x1.z, x1.w};

    float mx = v[0];
#pragma unroll
    for (int i = 1; i < 8; ++i) mx = fmaxf(mx, v[i]);
#pragma unroll
    for (int off = 32; off > 0; off >>= 1) mx = fmaxf(mx, __shfl_down(mx, off));
    if (lane == 0) red[wave] = mx;
    __syncthreads();
    if (tid == 0) red[4] = fmaxf(fmaxf(red[0], red[1]), fmaxf(red[2], red[3]));
    __syncthreads();
    mx = red[4];

    float e[8];
    float sum = 0.f;
#pragma unroll
    for (int i = 0; i < 8; ++i) {
        e[i] = exp2f((v[i] - mx) * 1.44269504088896f);
        sum += e[i];
    }
#pragma unroll
    for (int off = 32; off > 0; off >>= 1) sum += __shfl_down(sum, off);
    if (lane == 0) red[wave] = sum;
    __syncthreads();
    if (tid == 0) red[5] = red[0] + red[1] + red[2] + red[3];
    __syncthreads();
    float inv = 1.0f / red[5];

    f16x8 ov;
#pragma unroll
    for (int i = 0; i < 8; ++i) ov[i] = (_Float16)(e[i] * inv);
    *(f16x8*)(P + (size_t)row * 2048 + tid * 8) = ov;
}

extern "C" void kernel_launch(void* const* d_in, const int* in_sizes, int n_in,
                              void* d_out, int out_size, void* d_ws, size_t ws_size,
                              hipStream_t stream) {
    const float* enc = (const float*)d_in[0];  // [8,2048,512]
    const float* dec = (const float*)d_in[1];  // [8,1024,512]
    const float* Wq = (const float*)d_in[2];   // [512,512]
    const float* Wk = (const float*)d_in[3];
    const float* Wv = (const float*)d_in[4];
    float* out = (float*)d_out;                // [8,1024,512] fp32

    char* ws = (char*)d_ws;
    _Float16* qh = (_Float16*)(ws);
    _Float16* kh = (_Float16*)(ws + ((size_t)8 << 20));
    _Float16* P = (_Float16*)(ws);                       // aliases qh/kh after score
    _Float16* vt = (_Float16*)(ws + ((size_t)32 << 20));
    float* S = (float*)(ws + ((size_t)48 << 20));
    _Float16* dech = (_Float16*)(ws + ((size_t)48 << 20));  // dead before S written
    _Float16* wts = (_Float16*)(ws + ((size_t)56 << 20));   // dead before S written
    _Float16* ench = (_Float16*)(ws + ((size_t)112 << 20));

    dim3 blk(256);
    convert_f16<<<4096, blk, 0, stream>>>(enc, ench);
    convert_f16<<<2048, blk, 0, stream>>>(dec, dech);
    wtrans_kernel<<<dim3(8, 8, 3), blk, 0, stream>>>(Wq, Wk, Wv, wts);
    // Projections
    gemm_kernel<64, 0><<<dim3(4, 128, 1), blk, 0, stream>>>(
        dech, wts, qh, 512, 512, 512, 0, 0, 512);
    gemm_kernel<128, 0><<<dim3(4, 128, 1), blk, 0, stream>>>(
        ench, wts + 262144, kh, 512, 512, 512, 0, 0, 512);
    gemm_kernel<128, 1><<<dim3(4, 128, 1), blk, 0, stream>>>(
        ench, wts + 524288, vt, 512, 512, 512, 0, 0, 0);
    // Score: S[b,q,s] = q . k^T
    gemm_kernel<128, 2><<<dim3(16, 8, 8), blk, 0, stream>>>(
        qh, kh, S, 512, 512, 512, 1024, (long)2048 * 512, 2048);
    softmax_kernel<<<8192, blk, 0, stream>>>(S, P);
    // PV: out[b,q,u] = P . V   (512 blocks, 2/CU)
    gemm_kernel<64, 2><<<dim3(4, 16, 8), blk, 0, stream>>>(
        P, vt, out, 2048, 2048, 2048, 1024, (long)512 * 2048, 512);
}